// Round 1
// baseline (321.374 us; speedup 1.0000x reference)
//
#include <hip/hip_runtime.h>
#include <hip/hip_bf16.h>
#include <math.h>

#define DEVINL __device__ __forceinline__

typedef __attribute__((ext_vector_type(4))) float f32x4;
typedef __attribute__((ext_vector_type(8))) short s16x8;

DEVINL unsigned short f2bf(float f) {
  union { float f; unsigned u; } v; v.f = f;
  unsigned r = v.u + 0x7FFFu + ((v.u >> 16) & 1u);   // round-to-nearest-even
  return (unsigned short)(r >> 16);
}
DEVINL float bf2f(unsigned short s) {
  union { unsigned u; float f; } v; v.u = ((unsigned)s) << 16;
  return v.f;
}
DEVINL float gelu_exact(float x) {
  return 0.5f * x * (1.0f + erff(x * 0.70710678118654752f));
}

// ---------------------------------------------------------------------------
// x (f32) -> bf16 copy
// ---------------------------------------------------------------------------
__global__ __launch_bounds__(256) void conv_kernel(const float* __restrict__ x,
                                                   unsigned short* __restrict__ xb) {
  int i = blockIdx.x * 256 + threadIdx.x;   // over float4 units, grid sized exactly
  float4 v = ((const float4*)x)[i];
  uint2 u;
  u.x = (unsigned)f2bf(v.x) | ((unsigned)f2bf(v.y) << 16);
  u.y = (unsigned)f2bf(v.z) | ((unsigned)f2bf(v.w) << 16);
  ((uint2*)xb)[i] = u;
}

// ---------------------------------------------------------------------------
// Fused sim = x@x^T (split-bf16 MFMA, fp32-class accuracy) + top-9 per row.
// grid: (rowblock=16, batch=16), 256 threads, dynamic LDS 137472 B.
// ---------------------------------------------------------------------------
__global__ __launch_bounds__(256) void simtopk_kernel(const float* __restrict__ x,
                                                      int* __restrict__ graph) {
  const int tid  = threadIdx.x;
  const int lane = tid & 63;
  const int w    = tid >> 6;
  const int rb   = blockIdx.x;
  const int b    = blockIdx.y;

  extern __shared__ char smem[];
  unsigned short* rowsH = (unsigned short*)smem;        // [64][200] (pad breaks 128B stride)
  unsigned short* rowsL = rowsH + 64 * 200;
  unsigned short* colsH = rowsL + 64 * 200;
  unsigned short* colsL = colsH + 64 * 200;
  float* simt = (float*)(colsL + 64 * 200);             // [64][65]
  float* mv   = simt + 64 * 65;                         // [256][9]
  int*   mix  = (int*)(mv + 256 * 9);                   // [256][9]

  const float* xb = x + (size_t)b * (1024 * 192);

  // stage row block (hi/lo split)
  for (int i = tid; i < 64 * 48; i += 256) {
    int r = i / 48, kq = i - r * 48;
    float4 v = *(const float4*)(xb + (size_t)(rb * 64 + r) * 192 + kq * 4);
    float f[4] = {v.x, v.y, v.z, v.w};
#pragma unroll
    for (int j = 0; j < 4; ++j) {
      unsigned short hi = f2bf(f[j]);
      unsigned short lo = f2bf(f[j] - bf2f(hi));
      rowsH[r * 200 + kq * 4 + j] = hi;
      rowsL[r * 200 + kq * 4 + j] = lo;
    }
  }

  float tv[9]; int tix[9];
#pragma unroll
  for (int k = 0; k < 9; ++k) { tv[k] = -3.0e38f; tix[k] = 1 << 30; }

  const int wm = w >> 1, wn = w & 1;

  for (int ct = 0; ct < 16; ++ct) {
    // stage column tile (hi/lo split)
    for (int i = tid; i < 64 * 48; i += 256) {
      int r = i / 48, kq = i - r * 48;
      float4 v = *(const float4*)(xb + (size_t)(ct * 64 + r) * 192 + kq * 4);
      float f[4] = {v.x, v.y, v.z, v.w};
#pragma unroll
      for (int j = 0; j < 4; ++j) {
        unsigned short hi = f2bf(f[j]);
        unsigned short lo = f2bf(f[j] - bf2f(hi));
        colsH[r * 200 + kq * 4 + j] = hi;
        colsL[r * 200 + kq * 4 + j] = lo;
      }
    }
    __syncthreads();

    f32x4 acc[2][2];
#pragma unroll
    for (int a = 0; a < 2; ++a)
#pragma unroll
      for (int c = 0; c < 2; ++c) acc[a][c] = 0;

#pragma unroll
    for (int ks = 0; ks < 6; ++ks) {
      const int ko = ks * 32 + (lane >> 4) * 8;
      s16x8 ah[2], al[2], bh[2], bl[2];
#pragma unroll
      for (int m2 = 0; m2 < 2; ++m2) {
        int r = wm * 32 + m2 * 16 + (lane & 15);
        ah[m2] = *(const s16x8*)&rowsH[r * 200 + ko];
        al[m2] = *(const s16x8*)&rowsL[r * 200 + ko];
      }
#pragma unroll
      for (int n2 = 0; n2 < 2; ++n2) {
        int c = wn * 32 + n2 * 16 + (lane & 15);
        bh[n2] = *(const s16x8*)&colsH[c * 200 + ko];
        bl[n2] = *(const s16x8*)&colsL[c * 200 + ko];
      }
#pragma unroll
      for (int m2 = 0; m2 < 2; ++m2)
#pragma unroll
        for (int n2 = 0; n2 < 2; ++n2) {
          acc[m2][n2] = __builtin_amdgcn_mfma_f32_16x16x32_bf16(ah[m2], bh[n2], acc[m2][n2], 0, 0, 0);
          acc[m2][n2] = __builtin_amdgcn_mfma_f32_16x16x32_bf16(ah[m2], bl[n2], acc[m2][n2], 0, 0, 0);
          acc[m2][n2] = __builtin_amdgcn_mfma_f32_16x16x32_bf16(al[m2], bh[n2], acc[m2][n2], 0, 0, 0);
        }
    }

    // write sim tile (C/D: col=lane&15, row=(lane>>4)*4+reg — m89-verified)
#pragma unroll
    for (int m2 = 0; m2 < 2; ++m2)
#pragma unroll
      for (int n2 = 0; n2 < 2; ++n2)
#pragma unroll
        for (int r = 0; r < 4; ++r) {
          int rr = wm * 32 + m2 * 16 + (lane >> 4) * 4 + r;
          int cc = wn * 32 + n2 * 16 + (lane & 15);
          simt[rr * 65 + cc] = acc[m2][n2][r];
        }
    __syncthreads();

    // top-9 scan: 4 threads per row, 16 cols each
    {
      int r = tid >> 2, q = tid & 3;
#pragma unroll
      for (int j = 0; j < 16; ++j) {
        float v = simt[r * 65 + q * 16 + j];
        int   c = ct * 64 + q * 16 + j;
        if (v > tv[8]) {
          tv[8] = v; tix[8] = c;
#pragma unroll
          for (int s = 8; s > 0; --s) {
            if (tv[s] > tv[s - 1]) {  // strict: scan order keeps lower index first on ties
              float fv = tv[s]; tv[s] = tv[s - 1]; tv[s - 1] = fv;
              int   fi = tix[s]; tix[s] = tix[s - 1]; tix[s - 1] = fi;
            }
          }
        }
      }
    }
    __syncthreads();
  }

  // merge the 4 per-thread lists of each row
#pragma unroll
  for (int k = 0; k < 9; ++k) { mv[tid * 9 + k] = tv[k]; mix[tid * 9 + k] = tix[k]; }
  __syncthreads();
  if (tid < 64) {
    float fv[9]; int fi[9];
#pragma unroll
    for (int k = 0; k < 9; ++k) { fv[k] = -3.0e38f; fi[k] = 1 << 30; }
    for (int t = 0; t < 4; ++t) {
      int base = (tid * 4 + t) * 9;
#pragma unroll
      for (int k = 0; k < 9; ++k) {
        float v = mv[base + k]; int c = mix[base + k];
        bool better = (v > fv[8]) || (v == fv[8] && c < fi[8]);  // lax.top_k tie: lower idx
        if (better) {
          fv[8] = v; fi[8] = c;
#pragma unroll
          for (int s = 8; s > 0; --s) {
            bool up = (fv[s] > fv[s - 1]) || (fv[s] == fv[s - 1] && fi[s] < fi[s - 1]);
            if (up) {
              float a = fv[s]; fv[s] = fv[s - 1]; fv[s - 1] = a;
              int  ii = fi[s]; fi[s] = fi[s - 1]; fi[s - 1] = ii;
            }
          }
        }
      }
    }
    int* gout = graph + ((size_t)b * 1024 + rb * 64 + tid) * 9;
#pragma unroll
    for (int k = 0; k < 9; ++k) gout[k] = fi[k];
  }
}

// ---------------------------------------------------------------------------
// Gather-max aggregation + interleave: cat[...,2c]=h, cat[...,2c+1]=max_k(h[nbr]-h)
// ---------------------------------------------------------------------------
__global__ __launch_bounds__(256) void agg_kernel(const unsigned short* __restrict__ h,
                                                  const int* __restrict__ graph,
                                                  unsigned short* __restrict__ cat) {
  int gid  = blockIdx.x * 4 + (threadIdx.x >> 6);
  int lane = threadIdx.x & 63;
  int b = gid >> 10;
  int n = gid & 1023;
  const unsigned short* hb = h + (size_t)b * (1024 * 192);
  const int* g = graph + (size_t)gid * 9;
  float hn[3];
#pragma unroll
  for (int j = 0; j < 3; ++j) hn[j] = bf2f(hb[(size_t)n * 192 + lane + j * 64]);
  float ag[3] = {-3.0e38f, -3.0e38f, -3.0e38f};
  for (int k = 0; k < 9; ++k) {
    int idx = g[k];
#pragma unroll
    for (int j = 0; j < 3; ++j) {
      float v = bf2f(hb[(size_t)idx * 192 + lane + j * 64]) - hn[j];
      ag[j] = fmaxf(ag[j], v);
    }
  }
  unsigned* crow = (unsigned*)cat + (size_t)gid * 192;
#pragma unroll
  for (int j = 0; j < 3; ++j) {
    int c = lane + j * 64;
    crow[c] = (unsigned)f2bf(hn[j]) | ((unsigned)f2bf(ag[j]) << 16);
  }
}

// ---------------------------------------------------------------------------
// NT GEMM: out[m,n] = epi( sum_k A[m,k]*W[n,k] + bias[n] )
// A bf16 [M,K], W f32 [N,K] (converted to bf16 in staging). BM=128 BN=64 BK=64.
// ---------------------------------------------------------------------------
template <bool GELU_, bool RESID>
__global__ __launch_bounds__(256) void gemm_kernel(const unsigned short* __restrict__ A,
                                                   const float* __restrict__ W,
                                                   const float* __restrict__ bias,
                                                   const float* __restrict__ resid,
                                                   unsigned short* __restrict__ outb,
                                                   float* __restrict__ outf,
                                                   int N, int K) {
  __shared__ unsigned short As[2][128 * 64];
  __shared__ unsigned short Ws[2][64 * 64];

  const int tid  = threadIdx.x;
  const int lane = tid & 63;
  const int w    = tid >> 6;
  const int m0   = blockIdx.x * 128;
  const int n0   = blockIdx.y * 64;

  auto stageA = [&](int buf, int kt) {
    const unsigned short* gA = A + (size_t)m0 * K + kt * 64;
#pragma unroll
    for (int i = 0; i < 4; ++i) {
      int chunk = w * 4 + i;                                   // 1KB chunk = 8 rows
      const unsigned short* src = gA + (size_t)(chunk * 8 + (lane >> 3)) * K + (lane & 7) * 8;
      unsigned short* dst = &As[buf][chunk * 512];             // wave-uniform base
      __builtin_amdgcn_global_load_lds((const __attribute__((address_space(1))) void*)src,
                                       (__attribute__((address_space(3))) void*)dst, 16, 0, 0);
    }
  };
  auto stageW = [&](int buf, int kt) {
#pragma unroll
    for (int i = 0; i < 4; ++i) {
      int idx = tid + i * 256;                                 // 0..1023
      int n = idx >> 4, kq = idx & 15;
      float4 v = *(const float4*)(W + (size_t)(n0 + n) * K + kt * 64 + kq * 4);
      uint2 u;
      u.x = (unsigned)f2bf(v.x) | ((unsigned)f2bf(v.y) << 16);
      u.y = (unsigned)f2bf(v.z) | ((unsigned)f2bf(v.w) << 16);
      *(uint2*)&Ws[buf][n * 64 + kq * 4] = u;
    }
  };

  stageA(0, 0);
  stageW(0, 0);
  __syncthreads();

  const int wm = w >> 1, wn = w & 1;
  f32x4 acc[4][2];
#pragma unroll
  for (int a = 0; a < 4; ++a)
#pragma unroll
    for (int c = 0; c < 2; ++c) acc[a][c] = 0;

  const int nk = K >> 6;
  for (int kt = 0; kt < nk; ++kt) {
    const int cur = kt & 1;
    if (kt + 1 < nk) { stageA(cur ^ 1, kt + 1); stageW(cur ^ 1, kt + 1); }
#pragma unroll
    for (int ks = 0; ks < 2; ++ks) {
      const int ko = ks * 32 + (lane >> 4) * 8;
      s16x8 af[4], bfr[2];
#pragma unroll
      for (int m2 = 0; m2 < 4; ++m2)
        af[m2] = *(const s16x8*)&As[cur][(wm * 64 + m2 * 16 + (lane & 15)) * 64 + ko];
#pragma unroll
      for (int n2 = 0; n2 < 2; ++n2)
        bfr[n2] = *(const s16x8*)&Ws[cur][(wn * 32 + n2 * 16 + (lane & 15)) * 64 + ko];
#pragma unroll
      for (int m2 = 0; m2 < 4; ++m2)
#pragma unroll
        for (int n2 = 0; n2 < 2; ++n2)
          acc[m2][n2] = __builtin_amdgcn_mfma_f32_16x16x32_bf16(af[m2], bfr[n2], acc[m2][n2], 0, 0, 0);
    }
    __syncthreads();
  }

#pragma unroll
  for (int m2 = 0; m2 < 4; ++m2)
#pragma unroll
    for (int n2 = 0; n2 < 2; ++n2)
#pragma unroll
      for (int r = 0; r < 4; ++r) {
        int row = m0 + wm * 64 + m2 * 16 + (lane >> 4) * 4 + r;
        int col = n0 + wn * 32 + n2 * 16 + (lane & 15);
        float v = acc[m2][n2][r] + bias[col];
        if (GELU_) v = gelu_exact(v);
        if (RESID) v += resid[(size_t)row * N + col];
        size_t o = (size_t)row * N + col;
        if (outb) outb[o] = f2bf(v);
        if (outf) outf[o] = v;
      }
}

// ---------------------------------------------------------------------------
extern "C" void kernel_launch(void* const* d_in, const int* in_sizes, int n_in,
                              void* d_out, int out_size, void* d_ws, size_t ws_size,
                              hipStream_t stream) {
  (void)in_sizes; (void)n_in; (void)out_size; (void)ws_size;
  const float* x      = (const float*)d_in[0];
  const float* il1_w1 = (const float*)d_in[1];
  const float* il1_b1 = (const float*)d_in[2];
  const float* il1_w2 = (const float*)d_in[3];
  const float* il1_b2 = (const float*)d_in[4];
  const float* fc_w   = (const float*)d_in[5];
  const float* fc_b   = (const float*)d_in[6];
  const float* ol1_w1 = (const float*)d_in[7];
  const float* ol1_b1 = (const float*)d_in[8];
  const float* ol1_w2 = (const float*)d_in[9];
  const float* ol1_b2 = (const float*)d_in[10];
  const float* il2_w1 = (const float*)d_in[11];
  const float* il2_b1 = (const float*)d_in[12];
  const float* il2_w2 = (const float*)d_in[13];
  const float* il2_b2 = (const float*)d_in[14];
  const float* ol2_w1 = (const float*)d_in[15];
  const float* ol2_b1 = (const float*)d_in[16];
  const float* ol2_w2 = (const float*)d_in[17];
  const float* ol2_b2 = (const float*)d_in[18];

  char* ws = (char*)d_ws;
  const size_t SZ = 16384ull * 192 * 2;  // one bf16 [16384,192] tensor = 6291456 B
  unsigned short* xbf  = (unsigned short*)(ws);
  unsigned short* t13  = (unsigned short*)(ws + SZ);       // t1 then t3
  unsigned short* hbuf = (unsigned short*)(ws + 2 * SZ);   // h
  unsigned short* t2   = (unsigned short*)(ws + 3 * SZ);
  unsigned short* x1b  = (unsigned short*)(ws + 4 * SZ);
  unsigned short* catg = (unsigned short*)(ws + 5 * SZ);   // cat [16384,384] then g [16384,192]
  float*          x1f  = (float*)(ws + 7 * SZ);            // x1 f32
  unsigned short* uv   = (unsigned short*)(ws + 9 * SZ);   // u then v [16384,768]
  int*            graph = (int*)(ws + 13 * SZ);

  hipFuncSetAttribute((const void*)simtopk_kernel,
                      hipFuncAttributeMaxDynamicSharedMemorySize, 137472);

  conv_kernel<<<3072, 256, 0, stream>>>(x, xbf);
  simtopk_kernel<<<dim3(16, 16), 256, 137472, stream>>>(x, graph);
  // il1: t1 = gelu(x@w1^T+b1); h = t1@w2^T+b2
  gemm_kernel<true,  false><<<dim3(128, 3), 256, 0, stream>>>(xbf, il1_w1, il1_b1, nullptr, t13, nullptr, 192, 192);
  gemm_kernel<false, false><<<dim3(128, 3), 256, 0, stream>>>(t13, il1_w2, il1_b2, nullptr, hbuf, nullptr, 192, 192);
  agg_kernel<<<4096, 256, 0, stream>>>(hbuf, graph, catg);
  // t2 = gelu(cat@fc^T+fc_b)
  gemm_kernel<true,  false><<<dim3(128, 3), 256, 0, stream>>>(catg, fc_w, fc_b, nullptr, t2, nullptr, 192, 384);
  // ol1: t3 = gelu(t2@w1^T+b1); x1 = t3@w2^T+b2 + x
  gemm_kernel<true,  false><<<dim3(128, 3), 256, 0, stream>>>(t2, ol1_w1, ol1_b1, nullptr, t13, nullptr, 192, 192);
  gemm_kernel<false, true ><<<dim3(128, 3), 256, 0, stream>>>(t13, ol1_w2, ol1_b2, x, x1b, x1f, 192, 192);
  // il2: u = gelu(x1@w1^T+b1); g = gelu(u@w2^T+b2)  (external gelu fused)
  gemm_kernel<true,  false><<<dim3(128, 12), 256, 0, stream>>>(x1b, il2_w1, il2_b1, nullptr, uv, nullptr, 768, 192);
  gemm_kernel<true,  false><<<dim3(128, 3), 256, 0, stream>>>(uv, il2_w2, il2_b2, nullptr, catg, nullptr, 192, 768);
  // ol2: v = gelu(g@w1^T+b1); out = v@w2^T+b2 + x1
  gemm_kernel<true,  false><<<dim3(128, 12), 256, 0, stream>>>(catg, ol2_w1, ol2_b1, nullptr, uv, nullptr, 768, 192);
  gemm_kernel<false, true ><<<dim3(128, 3), 256, 0, stream>>>(uv, ol2_w2, ol2_b2, x1f, nullptr, (float*)d_out, 192, 768);
}